// Round 1
// baseline (207.517 us; speedup 1.0000x reference)
//
#include <hip/hip_runtime.h>
#include <math.h>

#define D_INNER 5120
#define DT_RANK 160
#define N_STATE 16
#define BATCH   256
#define KTOT    192              // 160 (dt_low) + 16 (B) + 16 (C)
#define SPLIT   32               // split-K for K1
#define CHUNK   (D_INNER / SPLIT) // 160

// ---- workspace layout (float offsets) ----
#define OFF_P     0
#define SZ_P      (SPLIT * BATCH * KTOT)      // 1,572,864 floats
#define OFF_T     (OFF_P + SZ_P)
#define SZ_T      (BATCH * KTOT)              // 49,152
#define OFF_WDTT  (OFF_T + SZ_T)
#define SZ_WDTT   (D_INNER * DT_RANK)         // 819,200
// total ~9.8 MB

// ---------------------------------------------------------------------------
// K0: transpose W_dt (160 x 5120) -> WdtT (5120 x 160) so K3 lanes can stream
// their column with float4 loads. Threads: (d, k-octet); reads coalesced over d.
// ---------------------------------------------------------------------------
__global__ __launch_bounds__(256) void k0_transpose(const float* __restrict__ Wdt,
                                                    float* __restrict__ ws) {
    int idx  = blockIdx.x * 256 + threadIdx.x;   // 0 .. 102399
    int d    = idx % D_INNER;                    // fastest -> coalesced reads
    int koct = idx / D_INNER;                    // 0..19 (uniform per block)
    int k0   = koct * 8;
    float r[8];
#pragma unroll
    for (int j = 0; j < 8; ++j) r[j] = Wdt[(k0 + j) * D_INNER + d];
    float4* o = (float4*)(ws + OFF_WDTT + d * DT_RANK + k0);
    o[0] = make_float4(r[0], r[1], r[2], r[3]);
    o[1] = make_float4(r[4], r[5], r[6], r[7]);
}

// ---------------------------------------------------------------------------
// K1: partial GEMM  T_partial[s][b][k] = sum_{dd in chunk s} x[b][dd] * W[dd][k]
// where W's 192 columns = [W_dt_low | W_B | W_C].
// 1 wave/block; lane -> column k in {lane, lane+64, lane+128};
// batch index b is wave-uniform -> x reads become s_load (SGPR FMA operand).
// Grid: (32 b-groups of 8, SPLIT).
// ---------------------------------------------------------------------------
__global__ __launch_bounds__(64) void k1_gemm(const float* __restrict__ x,
                                              const float* __restrict__ Wdtlow,
                                              const float* __restrict__ WB,
                                              const float* __restrict__ WC,
                                              float* __restrict__ ws) {
    const int lane = threadIdx.x;       // 0..63
    const int bg   = blockIdx.x;        // 0..31
    const int s    = blockIdx.y;        // 0..SPLIT-1
    const int b0   = bg * 8;
    const int dd0  = s * CHUNK;

    float acc[8][3];
#pragma unroll
    for (int i = 0; i < 8; ++i) { acc[i][0] = 0.f; acc[i][1] = 0.f; acc[i][2] = 0.f; }

    // column pointers: k=lane and k=64+lane are always in W_dt_low (stride 160).
    const float* pa = Wdtlow + dd0 * DT_RANK + lane;
    const float* pb = Wdtlow + dd0 * DT_RANK + 64 + lane;
    const float* pc;
    int strc;
    {
        int k2 = 128 + lane;
        if (k2 < DT_RANK)            { pc = Wdtlow + dd0 * DT_RANK + k2;          strc = DT_RANK; }
        else if (k2 < DT_RANK + 16)  { pc = WB + dd0 * N_STATE + (k2 - DT_RANK);  strc = N_STATE; }
        else                         { pc = WC + dd0 * N_STATE + (k2 - DT_RANK - 16); strc = N_STATE; }
    }

#pragma unroll 4
    for (int dd = 0; dd < CHUNK; ++dd) {
        float w0 = *pa; pa += DT_RANK;
        float w1 = *pb; pb += DT_RANK;
        float w2 = *pc; pc += strc;
#pragma unroll
        for (int i = 0; i < 8; ++i) {
            float xv = x[(b0 + i) * D_INNER + dd0 + dd];   // uniform -> s_load
            acc[i][0] += xv * w0;
            acc[i][1] += xv * w1;
            acc[i][2] += xv * w2;
        }
    }

    float* P = ws + OFF_P;
#pragma unroll
    for (int i = 0; i < 8; ++i) {
        float* Pp = P + ((s * BATCH) + b0 + i) * KTOT;
        Pp[lane]       = acc[i][0];
        Pp[lane + 64]  = acc[i][1];
        Pp[lane + 128] = acc[i][2];
    }
}

// ---------------------------------------------------------------------------
// K2: reduce split-K partials -> T[256][192]  (cols 0..159 = tmp, 160..175 = Bp,
// 176..191 = Cp)
// ---------------------------------------------------------------------------
__global__ __launch_bounds__(256) void k2_reduce(float* __restrict__ ws) {
    int g = blockIdx.x * 256 + threadIdx.x;    // < 49152
    const float* P = ws + OFF_P;
    float a = 0.f;
#pragma unroll
    for (int s = 0; s < SPLIT; ++s) a += P[s * (BATCH * KTOT) + g];
    ws[OFF_T + g] = a;
}

// ---------------------------------------------------------------------------
// K3: fused main kernel. 1 wave/block: lane -> d (64-wide d-tile), 4 batches
// per block (wave-uniform -> tmp/Bp/Cp via s_load).
//   delta = softplus(tmp @ W_dt + b_dt)       (WdtT float4-streamed per lane)
//   out   = x*D + sum_n exp(delta*A_n)*h0_n*Cp_n + delta*x*sum_n Bp_n*Cp_n
// ---------------------------------------------------------------------------
__global__ __launch_bounds__(64) void k3_main(const float* __restrict__ x,
                                              const float* __restrict__ b_dt,
                                              const float* __restrict__ A,
                                              const float* __restrict__ Dv,
                                              const float* __restrict__ h0,
                                              const float* __restrict__ ws,
                                              float* __restrict__ out) {
    const int lane = threadIdx.x;
    const int d    = blockIdx.x * 64 + lane;
    const int b0   = blockIdx.y * 4;

    const float* T    = ws + OFF_T;
    const float* WdtT = ws + OFF_WDTT;

    // ---- delta pre-activation GEMM: acc[i] = tmp[b0+i][:] . WdtT[d][:] ----
    float acc[4] = {0.f, 0.f, 0.f, 0.f};
    const float4* w4 = (const float4*)(WdtT + d * DT_RANK);
    const float* tp0 = T + (b0 + 0) * KTOT;
    const float* tp1 = T + (b0 + 1) * KTOT;
    const float* tp2 = T + (b0 + 2) * KTOT;
    const float* tp3 = T + (b0 + 3) * KTOT;

#pragma unroll 8
    for (int kq = 0; kq < DT_RANK / 4; ++kq) {
        float4 wv = w4[kq];
        int k = kq * 4;
        acc[0] += tp0[k] * wv.x + tp0[k + 1] * wv.y + tp0[k + 2] * wv.z + tp0[k + 3] * wv.w;
        acc[1] += tp1[k] * wv.x + tp1[k + 1] * wv.y + tp1[k + 2] * wv.z + tp1[k + 3] * wv.w;
        acc[2] += tp2[k] * wv.x + tp2[k + 1] * wv.y + tp2[k + 2] * wv.z + tp2[k + 3] * wv.w;
        acc[3] += tp3[k] * wv.x + tp3[k + 1] * wv.y + tp3[k + 2] * wv.z + tp3[k + 3] * wv.w;
    }

    // ---- per-d loads (reused across the 4 batches) ----
    const float bdt = b_dt[d];
    const float Dd  = Dv[d];
    float av[16];
    {
        const float4* a4 = (const float4*)(A + d * N_STATE);
        float4 a0 = a4[0], a1 = a4[1], a2 = a4[2], a3 = a4[3];
        av[0] = a0.x; av[1] = a0.y; av[2]  = a0.z; av[3]  = a0.w;
        av[4] = a1.x; av[5] = a1.y; av[6]  = a1.z; av[7]  = a1.w;
        av[8] = a2.x; av[9] = a2.y; av[10] = a2.z; av[11] = a2.w;
        av[12] = a3.x; av[13] = a3.y; av[14] = a3.z; av[15] = a3.w;
    }

#pragma unroll
    for (int i = 0; i < 4; ++i) {
        const int b = b0 + i;
        const float* Tb = T + b * KTOT;            // uniform row -> s_loads

        float v = acc[i] + bdt;
        float delta = (v > 20.f) ? v : log1pf(__expf(v));
        float xv = x[b * D_INNER + d];

        // Cp row + sum_n Bp_n * Cp_n (wave-uniform scalars)
        float cp[16];
        float sbc = 0.f;
#pragma unroll
        for (int n = 0; n < N_STATE; ++n) {
            cp[n] = Tb[176 + n];
            sbc += Tb[160 + n] * cp[n];
        }

        const float4* h4 = (const float4*)(h0 + ((size_t)b * D_INNER + d) * N_STATE);
        float4 h_0 = h4[0], h_1 = h4[1], h_2 = h4[2], h_3 = h4[3];

        float y = 0.f;
        y += __expf(delta * av[0])  * h_0.x * cp[0];
        y += __expf(delta * av[1])  * h_0.y * cp[1];
        y += __expf(delta * av[2])  * h_0.z * cp[2];
        y += __expf(delta * av[3])  * h_0.w * cp[3];
        y += __expf(delta * av[4])  * h_1.x * cp[4];
        y += __expf(delta * av[5])  * h_1.y * cp[5];
        y += __expf(delta * av[6])  * h_1.z * cp[6];
        y += __expf(delta * av[7])  * h_1.w * cp[7];
        y += __expf(delta * av[8])  * h_2.x * cp[8];
        y += __expf(delta * av[9])  * h_2.y * cp[9];
        y += __expf(delta * av[10]) * h_2.z * cp[10];
        y += __expf(delta * av[11]) * h_2.w * cp[11];
        y += __expf(delta * av[12]) * h_3.x * cp[12];
        y += __expf(delta * av[13]) * h_3.y * cp[13];
        y += __expf(delta * av[14]) * h_3.z * cp[14];
        y += __expf(delta * av[15]) * h_3.w * cp[15];

        out[b * D_INNER + d] = xv * (Dd + delta * sbc) + y;
    }
}

// ---------------------------------------------------------------------------
extern "C" void kernel_launch(void* const* d_in, const int* in_sizes, int n_in,
                              void* d_out, int out_size, void* d_ws, size_t ws_size,
                              hipStream_t stream) {
    const float* x      = (const float*)d_in[0];
    const float* Wdtlow = (const float*)d_in[1];
    const float* Wdt    = (const float*)d_in[2];
    const float* bdt    = (const float*)d_in[3];
    const float* WB     = (const float*)d_in[4];
    const float* WC     = (const float*)d_in[5];
    const float* A      = (const float*)d_in[6];
    const float* Dv     = (const float*)d_in[7];
    const float* h0     = (const float*)d_in[8];
    float* ws  = (float*)d_ws;
    float* out = (float*)d_out;

    // K0: transpose W_dt -> WdtT (5120*160)
    hipLaunchKernelGGL(k0_transpose, dim3((D_INNER * (DT_RANK / 8)) / 256), dim3(256),
                       0, stream, Wdt, ws);
    // K1: split-K projection GEMM partials
    hipLaunchKernelGGL(k1_gemm, dim3(BATCH / 8, SPLIT), dim3(64), 0, stream,
                       x, Wdtlow, WB, WC, ws);
    // K2: reduce partials -> T[256][192]
    hipLaunchKernelGGL(k2_reduce, dim3((BATCH * KTOT) / 256), dim3(256), 0, stream, ws);
    // K3: fused delta GEMM + softplus + SSM state update + output
    hipLaunchKernelGGL(k3_main, dim3(D_INNER / 64, BATCH / 4), dim3(64), 0, stream,
                       x, bdt, A, Dv, h0, ws, out);
}